// Round 7
// baseline (142.705 us; speedup 1.0000x reference)
//
#include <hip/hip_runtime.h>

// Problem geometry (fixed by setup_inputs): B=8, C=3, H=512, W=1024
#define HW_C   524288        // 512*1024 (power of two: p>>19 = batch, p&(HW-1) = hw)
#define NPIX   4194304       // 8*HW_C
#define NG     (NPIX / 4)    // float4 groups
#define GRID   1024
#define BLK    256
#define SLICE  (GRID * BLK)  // 262144; NG == 4*SLICE exactly -> 4 float4 groups per thread

// hardware transcendentals: v_log_f32 (log2), v_exp_f32 (2^x)
__device__ __forceinline__ float fast_pow04(float x) {
    // x in [0,1]; x==0 -> log2=-inf -> exp2=0 (matches pow(0,0.4))
    return __builtin_amdgcn_exp2f(0.4f * __builtin_amdgcn_logf(x));
}

__constant__ float c_night[19] = {
    (float)(76.5113984140019/255.0),  (float)(76.23163212875781/255.0),
    (float)(60.90662084364415/255.0), (float)(69.06930071129905/255.0),
    (float)(69.63671393061327/255.0), (float)(73.11413822794262/255.0),
    (float)(140.7827781957324/255.0), (float)(116.29554873008291/255.0),
    (float)(46.23329954488532/255.0), (float)(57.839322341112386/255.0),
    (float)(32.61465346757989/255.0), (float)(57.4385179294615/255.0),
    (float)(62.234896087294814/255.0),(float)(90.90285758569436/255.0),
    (float)(91.99610158117673/255.0), (float)(91.82209397173472/255.0),
    (float)(94.06478985576457/255.0), (float)(74.6924145472464/255.0),
    (float)(69.15034088822232/255.0)
};
__constant__ float c_city[19] = {
    (float)(86.46051320057052/255.0), (float)(79.37014543897092/255.0),
    (float)(95.30679177391578/255.0), (float)(71.11888521745776/255.0),
    (float)(75.57026559270716/255.0), (float)(77.90493757655786/255.0),
    (float)(74.77466800282637/255.0), (float)(88.27701037425895/255.0),
    (float)(57.685269557270146/255.0),(float)(72.71472387765841/255.0),
    (float)(229.9589238353863/255.0), (float)(66.9194012998903/255.0),
    (float)(60.42471796718752/255.0), (float)(76.8407421534007/255.0),
    (float)(74.98657626719087/255.0), (float)(73.56771430328095/255.0),
    (float)(123.92515568872523/255.0),(float)(68.93476495876828/255.0),
    (float)(76.0970460111028/255.0)
};

// -------- Pass 1: per-block min/max of illum0 = max3(org) - NIGHT[seg]. NO big stores. --------
__global__ __launch_bounds__(BLK, 4) void k_pass1(const float* __restrict__ org,
                                                  const int* __restrict__ seg,
                                                  float2* __restrict__ bmm)
{
    // lane-register table: lane l holds night[l]; lookup = ds_bpermute via __shfl
    const int lane = threadIdx.x & 63;
    const float night_reg = c_night[lane < 19 ? lane : 0];
    const int t = blockIdx.x * BLK + threadIdx.x;

    float4 R[4], G[4], Bc[4];
    int4   S[4];

    // issue ALL independent loads up front (16 x 16B per lane in flight)
    #pragma unroll
    for (int k = 0; k < 4; ++k) {
        const int p = (t + k * SLICE) << 2;
        const size_t base = (size_t)(p >> 19) * (3 * HW_C) + (p & (HW_C - 1));
        R[k]  = *(const float4*)(org + base);
        G[k]  = *(const float4*)(org + base + HW_C);
        Bc[k] = *(const float4*)(org + base + 2 * HW_C);
        S[k]  = *(const int4*)(seg + p);
    }

    float lmin = 1e30f, lmax = -1e30f;
    #pragma unroll
    for (int k = 0; k < 4; ++k) {
        float4 il;
        il.x = fmaxf(fmaxf(R[k].x, G[k].x), Bc[k].x) - __shfl(night_reg, S[k].x);
        il.y = fmaxf(fmaxf(R[k].y, G[k].y), Bc[k].y) - __shfl(night_reg, S[k].y);
        il.z = fmaxf(fmaxf(R[k].z, G[k].z), Bc[k].z) - __shfl(night_reg, S[k].z);
        il.w = fmaxf(fmaxf(R[k].w, G[k].w), Bc[k].w) - __shfl(night_reg, S[k].w);
        lmin = fminf(lmin, fminf(fminf(il.x, il.y), fminf(il.z, il.w)));
        lmax = fmaxf(lmax, fmaxf(fmaxf(il.x, il.y), fmaxf(il.z, il.w)));
    }

    // wave butterfly, then tiny LDS block reduce (end of kernel — barrier harmless here)
    #pragma unroll
    for (int m = 1; m < 64; m <<= 1) {
        lmin = fminf(lmin, __shfl_xor(lmin, m));
        lmax = fmaxf(lmax, __shfl_xor(lmax, m));
    }
    __shared__ float smin[BLK / 64], smax[BLK / 64];
    const int wave = threadIdx.x >> 6;
    if ((threadIdx.x & 63) == 0) { smin[wave] = lmin; smax[wave] = lmax; }
    __syncthreads();
    if (threadIdx.x == 0) {
        float m = smin[0], M = smax[0];
        #pragma unroll
        for (int w = 1; w < BLK / 64; ++w) { m = fminf(m, smin[w]); M = fmaxf(M, smax[w]); }
        bmm[blockIdx.x] = make_float2(m, M);   // plain store: no atomics, no init, no fences
    }
}

// -------- Pass 2: per-WAVE redundant bmm reduce (no mid-kernel barrier); RECOMPUTE illum
//          from org/seg (L3-hot after pass1); normalize/gamma/+CITY/clip; channel sums --------
__global__ __launch_bounds__(BLK, 4) void k_pass2(const float* __restrict__ refl,
                                                  const float* __restrict__ org,
                                                  const int* __restrict__ seg,
                                                  const float2* __restrict__ bmm,
                                                  double* __restrict__ partial)
{
    const int lane = threadIdx.x & 63;
    const float city_reg  = c_city[lane < 19 ? lane : 0];
    const float night_reg = c_night[lane < 19 ? lane : 0];
    const int t = blockIdx.x * BLK + threadIdx.x;

    // bmm as float4 loads: lane covers entries [2*(lane+k*64), +1], k<8 -> wave covers all 1024
    const float4* bmm4 = (const float4*)bmm;
    float4 mm[8];
    #pragma unroll
    for (int k = 0; k < 8; ++k) mm[k] = bmm4[lane + k * 64];

    int P[4];
    size_t baseA[4];
    #pragma unroll
    for (int k = 0; k < 4; ++k) {
        const int p = (t + k * SLICE) << 2;
        P[k] = p;
        baseA[k] = (size_t)(p >> 19) * (3 * HW_C) + (p & (HW_C - 1));
    }

    // org/seg loads (L3-hot: pass1 just streamed them; nothing evicted in between)
    float4 oR[4], oG[4], oB[4]; int4 sv[4];
    #pragma unroll
    for (int k = 0; k < 4; ++k) {
        oR[k] = *(const float4*)(org + baseA[k]);
        oG[k] = *(const float4*)(org + baseA[k] + HW_C);
        oB[k] = *(const float4*)(org + baseA[k] + 2 * HW_C);
        sv[k] = *(const int4*)(seg + P[k]);
    }

    // reduce mm while org/seg are in flight (waits only vmcnt for the mm loads),
    // then free the 32 mm registers before refl loads
    float lmin = fminf(mm[0].x, mm[0].z), lmax = fmaxf(mm[0].y, mm[0].w);
    #pragma unroll
    for (int k = 1; k < 8; ++k) {
        lmin = fminf(lmin, fminf(mm[k].x, mm[k].z));
        lmax = fmaxf(lmax, fmaxf(mm[k].y, mm[k].w));
    }
    #pragma unroll
    for (int m = 1; m < 64; m <<= 1) {
        lmin = fminf(lmin, __shfl_xor(lmin, m));
        lmax = fmaxf(lmax, __shfl_xor(lmax, m));
    }
    const float imin = lmin;
    const float inv  = 1.0f / (lmax - lmin);

    // recompute illum + city consts (frees org/seg registers)
    float4 il[4];
    float  c[4][4];
    #pragma unroll
    for (int k = 0; k < 4; ++k) {
        il[k].x = fmaxf(fmaxf(oR[k].x, oG[k].x), oB[k].x) - __shfl(night_reg, sv[k].x);
        il[k].y = fmaxf(fmaxf(oR[k].y, oG[k].y), oB[k].y) - __shfl(night_reg, sv[k].y);
        il[k].z = fmaxf(fmaxf(oR[k].z, oG[k].z), oB[k].z) - __shfl(night_reg, sv[k].z);
        il[k].w = fmaxf(fmaxf(oR[k].w, oG[k].w), oB[k].w) - __shfl(night_reg, sv[k].w);
        c[k][0] = __shfl(city_reg, sv[k].x); c[k][1] = __shfl(city_reg, sv[k].y);
        c[k][2] = __shfl(city_reg, sv[k].z); c[k][3] = __shfl(city_reg, sv[k].w);
    }

    // refl loads (HBM-cold) + fused z/sum compute
    float sr = 0.f, sg = 0.f, sb = 0.f;   // 16 pixels/thread: fp32 partials safe (<=16.0)
    #pragma unroll
    for (int k = 0; k < 4; ++k) {
        const float4 rr = *(const float4*)(refl + baseA[k]);
        const float4 gg = *(const float4*)(refl + baseA[k] + HW_C);
        const float4 bb = *(const float4*)(refl + baseA[k] + 2 * HW_C);
        float x, z;
        x = (il[k].x - imin) * inv; z = fminf(fmaxf(fast_pow04(x) + c[k][0], 0.f), 1.f);
        sr += rr.x * z; sg += gg.x * z; sb += bb.x * z;
        x = (il[k].y - imin) * inv; z = fminf(fmaxf(fast_pow04(x) + c[k][1], 0.f), 1.f);
        sr += rr.y * z; sg += gg.y * z; sb += bb.y * z;
        x = (il[k].z - imin) * inv; z = fminf(fmaxf(fast_pow04(x) + c[k][2], 0.f), 1.f);
        sr += rr.z * z; sg += gg.z * z; sb += bb.z * z;
        x = (il[k].w - imin) * inv; z = fminf(fmaxf(fast_pow04(x) + c[k][3], 0.f), 1.f);
        sr += rr.w * z; sg += gg.w * z; sb += bb.w * z;
    }

    // block reduce in double (single barrier, end of kernel)
    double vr = sr, vg = sg, vb = sb;
    for (int off = 32; off > 0; off >>= 1) {
        vr += __shfl_down(vr, off);
        vg += __shfl_down(vg, off);
        vb += __shfl_down(vb, off);
    }
    __shared__ double sh[3][BLK / 64];
    const int wave = threadIdx.x >> 6;
    if ((threadIdx.x & 63) == 0) { sh[0][wave] = vr; sh[1][wave] = vg; sh[2][wave] = vb; }
    __syncthreads();
    if (threadIdx.x == 0) {
        double tr = 0, tg = 0, tb = 0;
        #pragma unroll
        for (int w = 0; w < BLK / 64; ++w) { tr += sh[0][w]; tg += sh[1][w]; tb += sh[2][w]; }
        partial[3 * blockIdx.x + 0] = tr;
        partial[3 * blockIdx.x + 1] = tg;
        partial[3 * blockIdx.x + 2] = tb;
    }
}

// -------- Final: one block reduces 1024x3 doubles -> scalar loss --------
__global__ __launch_bounds__(BLK) void k_final(const double* __restrict__ partial,
                                               float* __restrict__ out)
{
    double sr = 0, sg = 0, sb = 0;
    for (int i = threadIdx.x; i < GRID; i += BLK) {
        sr += partial[3 * i + 0];
        sg += partial[3 * i + 1];
        sb += partial[3 * i + 2];
    }
    for (int off = 32; off > 0; off >>= 1) {
        sr += __shfl_down(sr, off);
        sg += __shfl_down(sg, off);
        sb += __shfl_down(sb, off);
    }
    __shared__ double sh[3][BLK / 64];
    const int wave = threadIdx.x >> 6;
    if ((threadIdx.x & 63) == 0) { sh[0][wave] = sr; sh[1][wave] = sg; sh[2][wave] = sb; }
    __syncthreads();
    if (threadIdx.x == 0) {
        double tr = 0, tg = 0, tb = 0;
        #pragma unroll
        for (int w = 0; w < BLK / 64; ++w) { tr += sh[0][w]; tg += sh[1][w]; tb += sh[2][w]; }
        const double n = (double)NPIX;
        const double r = tr / n, g = tg / n, b = tb / n;
        out[0] = (float)((r - g) * (r - g) + (r - b) * (r - b) + (g - b) * (g - b));
    }
}

extern "C" void kernel_launch(void* const* d_in, const int* in_sizes, int n_in,
                              void* d_out, int out_size, void* d_ws, size_t ws_size,
                              hipStream_t stream) {
    const float* refl = (const float*)d_in[0];
    const float* org  = (const float*)d_in[1];
    const int*   seg  = (const int*)d_in[2];
    float* out = (float*)d_out;

    unsigned char* wsb = (unsigned char*)d_ws;
    float2*  bmm     = (float2*)(wsb);                     // @0     8 KiB
    double*  partial = (double*)(wsb + 16384);             // @16K  24 KiB

    k_pass1<<<GRID, BLK, 0, stream>>>(org, seg, bmm);
    k_pass2<<<GRID, BLK, 0, stream>>>(refl, org, seg, bmm, partial);
    k_final<<<1, BLK, 0, stream>>>(partial, out);
}